// Round 18
// baseline (167.620 us; speedup 1.0000x reference)
//
#include <hip/hip_runtime.h>
#include <hip/hip_fp16.h>

#define D 64
#define RB 512           // rows per coarse bucket (b = row>>9)
#define RB_SHIFT 9
#define COL_BITS 18      // n_total = 150001 < 2^18; row_local in bits 18..26
#define COL_MASK 0x3FFFF
#define CHUNK 4096       // edges per partition block (489 blocks)
#define FT 512           // threads for hist/fill kernels

// ---------------------------------------------------------------------------
// FUSED: per-chunk bucket histogram + f16 table conversion slice + zero-init
// of cursors/output (block 0; later dispatches see the writes in-stream).
__global__ void convhist_kernel(const float* __restrict__ user_emb,
                                const float* __restrict__ item_emb,
                                __half* __restrict__ tbl,
                                int n_user_rows, int n_total,
                                const int* __restrict__ row,
                                int* __restrict__ hist, int n_edges, int nb,
                                int* __restrict__ cursor,
                                float* __restrict__ out) {
    __shared__ int h[RB];
    int blk = blockIdx.x;
    if (blk == 0) {
        if (threadIdx.x < 2) cursor[threadIdx.x] = 0;
        if (threadIdx.x == 0) out[0] = 0.0f;
    }
    for (int i = threadIdx.x; i < nb; i += FT) h[i] = 0;
    __syncthreads();
    int s = blk * CHUNK;
    int e = min(s + CHUNK, n_edges);
    for (int k = s + threadIdx.x; k < e; k += FT)
        atomicAdd(&h[row[k] >> RB_SHIFT], 1);
    __syncthreads();
    for (int i = threadIdx.x; i < nb; i += FT)
        hist[blk * nb + i] = h[i];   // coalesced row write
    // conversion slice (f32 -> f16)
    size_t t = (size_t)blk * FT + threadIdx.x;
    size_t total4 = (size_t)n_total * (D / 4);
    size_t user4 = (size_t)n_user_rows * (D / 4);
    size_t stride = (size_t)gridDim.x * FT;
    for (size_t i = t; i < total4; i += stride) {
        float4 v = (i < user4) ? reinterpret_cast<const float4*>(user_emb)[i]
                               : reinterpret_cast<const float4*>(item_emb)[i - user4];
        __half2 h01 = __halves2half2(__float2half_rn(v.x), __float2half_rn(v.y));
        __half2 h23 = __halves2half2(__float2half_rn(v.z), __float2half_rn(v.w));
        uint2 o;
        o.x = *reinterpret_cast<unsigned*>(&h01);
        o.y = *reinterpret_cast<unsigned*>(&h23);
        reinterpret_cast<uint2*>(tbl)[i] = o;
    }
}

// ---------------------------------------------------------------------------
// FUSED col_sum + scan + col_scan: ONE WAVE per bucket; atomic span alloc.
__global__ void col_alloc_kernel(int* __restrict__ hist,
                                 int* __restrict__ cstart, int* __restrict__ cend,
                                 int* __restrict__ cursor, int nb, int nblk) {
    int w = (blockIdx.x * blockDim.x + threadIdx.x) >> 6;
    int lane = threadIdx.x & 63;
    if (w >= nb) return;
    int ssum = 0;
    for (int blk = lane; blk < nblk; blk += 64)
        ssum += hist[blk * nb + w];
    for (int off = 32; off > 0; off >>= 1)
        ssum += __shfl_down(ssum, off, 64);
    int base = 0;
    if (lane == 0) base = atomicAdd(cursor, ssum);
    base = __shfl(base, 0, 64);
    int run = base;
    int total = __shfl(ssum, 0, 64);
    if (lane == 0) { cstart[w] = base; cend[w] = base + total; }
    for (int b0 = 0; b0 < nblk; b0 += 64) {
        int blk = b0 + lane;
        int v = (blk < nblk) ? hist[blk * nb + w] : 0;
        int inc = v;
#pragma unroll
        for (int off = 1; off < 64; off <<= 1) {
            int t = __shfl_up(inc, off, 64);
            if (lane >= off) inc += t;
        }
        if (blk < nblk) hist[blk * nb + w] = run + (inc - v);
        run += __shfl(inc, 63, 64);   // chunk total
    }
}

// ---------------------------------------------------------------------------
// Pass C: LDS-sorted fill. Rank edges via LDS histogram atomic returns,
// shuffle-scan the bucket counts, place (data, global addr) into LDS in
// bucket-sorted order, then drain with coalesced run writes.
__global__ void fill_exact_kernel(const int* __restrict__ row, const int* __restrict__ col,
                                  const float* __restrict__ val, const int* __restrict__ hist,
                                  int2* __restrict__ stage, int n_edges, int nb) {
    __shared__ int hloc[RB];
    __shared__ int lbase[RB];
    __shared__ int gbase[RB];
    __shared__ int wsum[FT / 64];
    __shared__ int2 sdata[CHUNK];   // 32 KB
    __shared__ int  saddr[CHUNK];   // 16 KB
    int blk = blockIdx.x;
    int tid = threadIdx.x;
    int lane = tid & 63, wid = tid >> 6;
    for (int i = tid; i < nb; i += FT) {
        hloc[i] = 0;
        gbase[i] = hist[blk * nb + i];
    }
    __syncthreads();
    int s = blk * CHUNK;
    int e = min(s + CHUNK, n_edges);
    int cnt = e - s;
    int2 data[8];
    int bkt[8], rnk[8];
    int nloc = 0;
#pragma unroll
    for (int j = 0; j < 8; ++j) {
        int k = s + j * FT + tid;
        if (k < e) {
            int r = row[k];
            int b = r >> RB_SHIFT;
            data[nloc] = make_int2(col[k] | ((r & (RB - 1)) << COL_BITS),
                                   __float_as_int(val[k]));
            bkt[nloc] = b;
            rnk[nloc] = atomicAdd(&hloc[b], 1);
            ++nloc;
        }
    }
    __syncthreads();
    // exclusive scan of hloc[0..nb) -> lbase (shfl + cross-wave)
    int v = (tid < nb) ? hloc[tid] : 0;
    int inc = v;
#pragma unroll
    for (int off = 1; off < 64; off <<= 1) {
        int t = __shfl_up(inc, off, 64);
        if (lane >= off) inc += t;
    }
    if (lane == 63) wsum[wid] = inc;
    __syncthreads();
    if (wid == 0) {
        int wv = (lane < FT / 64) ? wsum[lane] : 0;
        int wi = wv;
#pragma unroll
        for (int off = 1; off < FT / 64; off <<= 1) {
            int t = __shfl_up(wi, off, 64);
            if (lane >= off) wi += t;
        }
        if (lane < FT / 64) wsum[lane] = wi - wv;   // exclusive
    }
    __syncthreads();
    if (tid < nb) lbase[tid] = (inc - v) + wsum[wid];
    __syncthreads();
    // place into LDS sorted order with precomputed global addresses
    for (int j = 0; j < nloc; ++j) {
        int b = bkt[j];
        int pos = lbase[b] + rnk[j];
        sdata[pos] = data[j];
        saddr[pos] = gbase[b] + rnk[j];
    }
    __syncthreads();
    // drain: consecutive threads -> consecutive addresses within runs
    for (int j = tid; j < cnt; j += FT)
        stage[saddr[j]] = sdata[j];
}

// ---------------------------------------------------------------------------
// FUSED bucket finalize: row histogram -> padded shfl-scan -> atomic span
// alloc -> per-row {start,end} -> pad fill -> row-sorted scatter. Weight
// stored as replicated half2 so spmm needs zero decode ops.
__global__ void bucket_pad_kernel(const int* __restrict__ cstart,
                                  const int* __restrict__ cend,
                                  const int2* __restrict__ stage,
                                  int2* __restrict__ offs,
                                  int2* __restrict__ pairs,
                                  int* __restrict__ cursor, int n_total) {
    __shared__ int sc[RB];
    __shared__ int cur[RB];
    __shared__ int wsum[RB / 64];
    __shared__ int pbase_s;
    int b = blockIdx.x;
    int tid = threadIdx.x;
    int lane = tid & 63, wid = tid >> 6;
    int s = cstart[b], e = cend[b];
    sc[tid] = 0;
    __syncthreads();
    for (int k = s + tid; k < e; k += RB)
        atomicAdd(&sc[stage[k].x >> COL_BITS], 1);
    __syncthreads();
    int cnt = sc[tid];
    int pad = (cnt + 3) & ~3;
    int inc = pad;
#pragma unroll
    for (int off = 1; off < 64; off <<= 1) {
        int t = __shfl_up(inc, off, 64);
        if (lane >= off) inc += t;
    }
    if (lane == 63) wsum[wid] = inc;
    __syncthreads();
    if (wid == 0) {
        int wv = (lane < RB / 64) ? wsum[lane] : 0;
        int wi = wv;
#pragma unroll
        for (int off = 1; off < RB / 64; off <<= 1) {
            int t = __shfl_up(wi, off, 64);
            if (lane >= off) wi += t;
        }
        if (lane < RB / 64) wsum[lane] = wi - wv;   // exclusive
    }
    __syncthreads();
    int incl = inc + wsum[wid];
    if (tid == RB - 1) pbase_s = atomicAdd(cursor, incl);
    __syncthreads();
    int start = pbase_s + incl - pad;   // exclusive padded prefix
    int r = b * RB + tid;
    if (r < n_total) offs[r] = make_int2(start, start + pad);
    cur[tid] = start;
    for (int q = start + cnt; q < start + pad; ++q)
        pairs[q] = make_int2(0, 0);   // col 0, weight half2(0,0)
    __syncthreads();
    for (int k = s + tid; k < e; k += RB) {
        int2 p = stage[k];
        int rl = p.x >> COL_BITS;
        int pos = atomicAdd(&cur[rl], 1);
        __half hw = __float2half_rn(__int_as_float(p.y));
        unsigned hb = (unsigned)*reinterpret_cast<unsigned short*>(&hw);
        pairs[pos] = make_int2(p.x & COL_MASK, (int)(hb | (hb << 16)));
    }
}

// ---------------------------------------------------------------------------
// shared gather core: 8-lane group accumulates one row from src (f16, padded
// to multiples of 4 edges; tail-free; 8/4 unroll; uint4 pair loads)
__device__ __forceinline__ void gather_row(int2 oo, const int2* __restrict__ pairs,
                                           const uint4* __restrict__ s4, int sub,
                                           __half2 acc[4]) {
    int k = oo.x;
    int end = oo.y;
    acc[0] = __float2half2_rn(0.f);
    acc[1] = acc[0]; acc[2] = acc[0]; acc[3] = acc[0];
    for (; k + 8 <= end; k += 8) {
        uint4 q[4];
#pragma unroll
        for (int j = 0; j < 4; ++j)
            q[j] = reinterpret_cast<const uint4*>(pairs + k)[j];
        uint4 rr[8];
#pragma unroll
        for (int j = 0; j < 4; ++j) {
            rr[2 * j]     = s4[(size_t)q[j].x * 8 + sub];
            rr[2 * j + 1] = s4[(size_t)q[j].z * 8 + sub];
        }
#pragma unroll
        for (int j = 0; j < 4; ++j) {
            __half2 w0 = *reinterpret_cast<__half2*>(&q[j].y);
            __half2 w1 = *reinterpret_cast<__half2*>(&q[j].w);
            const __half2* r0 = reinterpret_cast<const __half2*>(&rr[2 * j]);
            const __half2* r1 = reinterpret_cast<const __half2*>(&rr[2 * j + 1]);
            acc[0] = __hfma2(r0[0], w0, acc[0]);
            acc[1] = __hfma2(r0[1], w0, acc[1]);
            acc[2] = __hfma2(r0[2], w0, acc[2]);
            acc[3] = __hfma2(r0[3], w0, acc[3]);
            acc[0] = __hfma2(r1[0], w1, acc[0]);
            acc[1] = __hfma2(r1[1], w1, acc[1]);
            acc[2] = __hfma2(r1[2], w1, acc[2]);
            acc[3] = __hfma2(r1[3], w1, acc[3]);
        }
    }
    if (k < end) {   // exactly 4 remain (padded)
        uint4 q[2];
        q[0] = reinterpret_cast<const uint4*>(pairs + k)[0];
        q[1] = reinterpret_cast<const uint4*>(pairs + k)[1];
        uint4 rr[4];
#pragma unroll
        for (int j = 0; j < 2; ++j) {
            rr[2 * j]     = s4[(size_t)q[j].x * 8 + sub];
            rr[2 * j + 1] = s4[(size_t)q[j].z * 8 + sub];
        }
#pragma unroll
        for (int j = 0; j < 2; ++j) {
            __half2 w0 = *reinterpret_cast<__half2*>(&q[j].y);
            __half2 w1 = *reinterpret_cast<__half2*>(&q[j].w);
            const __half2* r0 = reinterpret_cast<const __half2*>(&rr[2 * j]);
            const __half2* r1 = reinterpret_cast<const __half2*>(&rr[2 * j + 1]);
            acc[0] = __hfma2(r0[0], w0, acc[0]);
            acc[1] = __hfma2(r0[1], w0, acc[1]);
            acc[2] = __hfma2(r0[2], w0, acc[2]);
            acc[3] = __hfma2(r0[3], w0, acc[3]);
            acc[0] = __hfma2(r1[0], w1, acc[0]);
            acc[1] = __hfma2(r1[1], w1, acc[1]);
            acc[2] = __hfma2(r1[2], w1, acc[2]);
            acc[3] = __hfma2(r1[3], w1, acc[3]);
        }
    }
}

// ---------------------------------------------------------------------------
// gather spmm + FUSED batch accumulation. Blocks < main_blocks: propagate all
// rows src->dst. Extra blocks: recompute the batch rows' layer value from src
// (independent of dst) and init (MODE 0, + f32 emb) or accumulate (MODE 1)
// into u_acc/v_acc.
template <int MODE>
__global__ void spmm_gather_kernel(const int2* __restrict__ offs,
                                   const int2* __restrict__ pairs,
                                   const __half* __restrict__ src,
                                   __half* __restrict__ dst, int n_total,
                                   int main_blocks,
                                   const int* __restrict__ users,
                                   const int* __restrict__ items,
                                   const float* __restrict__ user_emb,
                                   const float* __restrict__ item_emb,
                                   float* __restrict__ u_acc,
                                   float* __restrict__ v_acc, int batch,
                                   int n_user_rows) {
    const uint4* s4 = reinterpret_cast<const uint4*>(src);
    if ((int)blockIdx.x < main_blocks) {
        int t = blockIdx.x * blockDim.x + threadIdx.x;
        int r = t >> 3;
        int sub = t & 7;
        if (r >= n_total) return;
        __half2 acc[4];
        gather_row(offs[r], pairs, s4, sub, acc);
        reinterpret_cast<uint4*>(dst + (size_t)r * D)[sub] =
            *reinterpret_cast<uint4*>(acc);
    } else {
        int t = (blockIdx.x - main_blocks) * blockDim.x + threadIdx.x;
        int g = t >> 3;          // batch element*2
        int sub = t & 7;
        if (g >= batch * 2) return;
        int b = g >> 1;
        int side = g & 1;
        int idx = (side == 0) ? users[b] : items[b];
        int row = (side == 0) ? idx : (n_user_rows + idx);
        __half2 acc[4];
        gather_row(offs[row], pairs, s4, sub, acc);
        float2 f0 = __half22float2(acc[0]), f1 = __half22float2(acc[1]);
        float2 f2 = __half22float2(acc[2]), f3 = __half22float2(acc[3]);
        float4 lo = make_float4(f0.x, f0.y, f1.x, f1.y);
        float4 hi = make_float4(f2.x, f2.y, f3.x, f3.y);
        float* accp = ((side == 0) ? u_acc : v_acc) + (size_t)b * D + sub * 8;
        if (MODE == 0) {
            const float* emb = (side == 0) ? (user_emb + (size_t)idx * D)
                                           : (item_emb + (size_t)idx * D);
            float4 e0 = reinterpret_cast<const float4*>(emb)[sub * 2];
            float4 e1 = reinterpret_cast<const float4*>(emb)[sub * 2 + 1];
            lo.x += e0.x; lo.y += e0.y; lo.z += e0.z; lo.w += e0.w;
            hi.x += e1.x; hi.y += e1.y; hi.z += e1.z; hi.w += e1.w;
        } else {
            float4 a0 = reinterpret_cast<const float4*>(accp)[0];
            float4 a1 = reinterpret_cast<const float4*>(accp)[1];
            lo.x += a0.x; lo.y += a0.y; lo.z += a0.z; lo.w += a0.w;
            hi.x += a1.x; hi.y += a1.y; hi.z += a1.z; hi.w += a1.w;
        }
        reinterpret_cast<float4*>(accp)[0] = lo;
        reinterpret_cast<float4*>(accp)[1] = hi;
    }
}

// ---------------------------------------------------------------------------
// Fused final stage: per batch element, compute layer-3 ONLY for its user row
// and item row (4-unrolled, tail-free), add accumulators, dot, BCE, reduce.
__global__ void batch_l3_loss_kernel(const int* __restrict__ users,
                                     const int* __restrict__ items,
                                     const int2* __restrict__ offs,
                                     const int2* __restrict__ pairs,
                                     const __half* __restrict__ buf,
                                     const float* __restrict__ u_acc,
                                     const float* __restrict__ v_acc,
                                     const float* __restrict__ labels,
                                     float* __restrict__ out,
                                     int batch, int n_user_rows) {
    int t = blockIdx.x * blockDim.x + threadIdx.x;
    int b = t >> 3;
    int sub = t & 7;
    const uint4* s4 = reinterpret_cast<const uint4*>(buf);
    float lb = 0.0f;
    if (b < batch) {
        __half2 au[4], av[4];
        gather_row(offs[users[b]], pairs, s4, sub, au);
        gather_row(offs[n_user_rows + items[b]], pairs, s4, sub, av);
        const float4* ua = reinterpret_cast<const float4*>(u_acc + (size_t)b * D);
        const float4* va = reinterpret_cast<const float4*>(v_acc + (size_t)b * D);
        float4 u0 = ua[sub * 2], u1 = ua[sub * 2 + 1];
        float4 v0 = va[sub * 2], v1 = va[sub * 2 + 1];
        float2 a0 = __half22float2(au[0]), a1 = __half22float2(au[1]);
        float2 a2 = __half22float2(au[2]), a3 = __half22float2(au[3]);
        float2 c0 = __half22float2(av[0]), c1 = __half22float2(av[1]);
        float2 c2 = __half22float2(av[2]), c3 = __half22float2(av[3]);
        float partial =
            (u0.x + a0.x) * (v0.x + c0.x) + (u0.y + a0.y) * (v0.y + c0.y) +
            (u0.z + a1.x) * (v0.z + c1.x) + (u0.w + a1.y) * (v0.w + c1.y) +
            (u1.x + a2.x) * (v1.x + c2.x) + (u1.y + a2.y) * (v1.y + c2.y) +
            (u1.z + a3.x) * (v1.z + c3.x) + (u1.w + a3.y) * (v1.w + c3.y);
        partial += __shfl_xor(partial, 1, 64);
        partial += __shfl_xor(partial, 2, 64);
        partial += __shfl_xor(partial, 4, 64);
        if (sub == 0) {
            float g = partial * (1.0f / 16.0f);
            float y = labels[b];
            lb = fmaxf(g, 0.0f) - g * y + log1pf(expf(-fabsf(g)));
        }
    }
    lb += __shfl_xor(lb, 8, 64);
    lb += __shfl_xor(lb, 16, 64);
    lb += __shfl_xor(lb, 32, 64);
    __shared__ float sd[4];
    int wid = threadIdx.x >> 6;
    if ((threadIdx.x & 63) == 0) sd[wid] = lb;
    __syncthreads();
    if (threadIdx.x == 0)
        atomicAdd(out, (sd[0] + sd[1] + sd[2] + sd[3]) / (float)batch);
}

// ---------------------------------------------------------------------------
extern "C" void kernel_launch(void* const* d_in, const int* in_sizes, int n_in,
                              void* d_out, int out_size, void* d_ws, size_t ws_size,
                              hipStream_t stream) {
    const int* users = (const int*)d_in[0];
    const int* items = (const int*)d_in[1];
    const float* labels = (const float*)d_in[2];
    const int* edge_row = (const int*)d_in[3];
    const int* edge_col = (const int*)d_in[4];
    const float* edge_val = (const float*)d_in[5];
    const float* user_emb = (const float*)d_in[6];
    const float* item_emb = (const float*)d_in[7];

    const int batch = in_sizes[0];
    const int n_edges = in_sizes[3];
    const int n_user_rows = in_sizes[6] / D;   // 100001
    const int n_item_rows = in_sizes[7] / D;   // 50000
    const int n_total = n_user_rows + n_item_rows;
    const int nb = (n_total + RB - 1) / RB;          // 293
    const int nblk = (n_edges + CHUNK - 1) / CHUNK;  // 489
    const int L = nb * nblk;                          // 143,277
    const int max_pairs = n_edges + 3 * nb * RB;      // padded upper bound

    auto align256 = [](size_t x) { return (x + 255) & ~(size_t)255; };
    const size_t tblb_bytes = align256((size_t)n_total * D * 2);            // 19.2 MB f16
    const size_t acc_bytes = align256((size_t)batch * D * sizeof(float));   // 2 MB
    const size_t offs_bytes = align256((size_t)n_total * sizeof(int2));     // 1.2 MB
    const size_t pairs_bytes = align256((size_t)max_pairs * sizeof(int2));  // ~19.6 MB
    const size_t hist_bytes = align256((size_t)L * sizeof(int));            // 573 KB
    const size_t cse_bytes = align256((size_t)nb * sizeof(int));

    char* ws = (char*)d_ws;
    __half* tbl  = (__half*)ws;                  ws += tblb_bytes;
    __half* buf0 = (__half*)ws;                  ws += tblb_bytes;
    __half* buf1 = (__half*)ws;                  ws += tblb_bytes;
    float* u_acc  = (float*)ws;                  ws += acc_bytes;
    float* v_acc  = (float*)ws;                  ws += acc_bytes;
    int2*  offs   = (int2*)ws;                   ws += offs_bytes;
    int2*  pairs  = (int2*)ws;                   ws += pairs_bytes;
    int*   cursor = (int*)ws;                    ws += 256;
    // stage (16 MB) dead before spmm layer 1 writes buf0 -> alias
    int2*  stage  = (int2*)buf0;
    // CSR-build scratch dead before spmm layer 2 writes buf1 -> alias
    char* sb = (char*)buf1;
    int* hist   = (int*)sb;                      sb += hist_bytes;
    int* cstart = (int*)sb;                      sb += cse_bytes;
    int* cend   = (int*)sb;                      sb += cse_bytes;

    // ---- fused f16 conversion + per-chunk histogram + zero-init ----
    convhist_kernel<<<nblk, FT, 0, stream>>>(user_emb, item_emb, tbl,
                                             n_user_rows, n_total,
                                             edge_row, hist, n_edges, nb,
                                             cursor, (float*)d_out);

    // ---- fused column alloc+scan (atomic span allocation per bucket) ----
    const int wave_blocks = (nb + 3) / 4;
    col_alloc_kernel<<<wave_blocks, 256, 0, stream>>>(hist, cstart, cend,
                                                      &cursor[0], nb, nblk);
    fill_exact_kernel<<<nblk, FT, 0, stream>>>(edge_row, edge_col, edge_val,
                                               hist, stage, n_edges, nb);
    bucket_pad_kernel<<<nb, RB, 0, stream>>>(cstart, cend, stage, offs, pairs,
                                             &cursor[1], n_total);

    // ---- layers 1,2 propagation + fused batch accumulation ----
    const int main_blocks = (int)(((size_t)n_total * 8 + 255) / 256);
    const int bat_blocks = (batch * 2 * 8 + 255) / 256;
    const int spmm_grid = main_blocks + bat_blocks;
    spmm_gather_kernel<0><<<spmm_grid, 256, 0, stream>>>(
        offs, pairs, tbl, buf0, n_total, main_blocks,
        users, items, user_emb, item_emb, u_acc, v_acc, batch, n_user_rows);
    spmm_gather_kernel<1><<<spmm_grid, 256, 0, stream>>>(
        offs, pairs, buf0, buf1, n_total, main_blocks,
        users, items, user_emb, item_emb, u_acc, v_acc, batch, n_user_rows);

    // ---- layer 3 computed ONLY at batch rows, fused with dot + BCE loss ----
    const int bl_blocks = (batch * 8 + 255) / 256;
    batch_l3_loss_kernel<<<bl_blocks, 256, 0, stream>>>(users, items, offs, pairs,
                                                        buf1, u_acc, v_acc, labels,
                                                        (float*)d_out, batch, n_user_rows);
}